// Round 1
// baseline (102.639 us; speedup 1.0000x reference)
//
#include <hip/hip_runtime.h>
#include <math.h>

namespace {
constexpr int kB  = 16;
constexpr int kNV = 6890;
constexpr int kNF = 13776;
constexpr int kTF = 2 * kNF;      // 27552 triangles per person-pair
constexpr int kP  = kB / 2;       // 8 pairs
constexpr int kC  = 65536;
}
#define SIGMA_F 1e-4f
#define EPS_F   1e-9f
#define THRESH_F 2000.0f
#define WEIGHT_F 0.1f

__global__ void init_sums_kernel(float* __restrict__ sums) {
    int t = threadIdx.x;
    if (t < kP) sums[t] = 0.0f;
}

// One thread per (pair, triangle): build padded triangle buffer tri[g][3] as float4
__global__ void build_tris_kernel(const float* __restrict__ verts,
                                  const float* __restrict__ trans,
                                  const int*   __restrict__ faces,
                                  float* __restrict__ tri) {
    int g = blockIdx.x * blockDim.x + threadIdx.x;
    if (g >= kP * kTF) return;
    int p = g / kTF;
    int t = g - p * kTF;
    int half = (t >= kNF) ? 1 : 0;
    int b = 2 * p + half;
    int f = t - half * kNF;
    float tx = trans[3 * b + 0];
    float ty = trans[3 * b + 1];
    float tz = trans[3 * b + 2];
    float4* dst = (float4*)(tri + (size_t)g * 12);
#pragma unroll
    for (int k = 0; k < 3; ++k) {
        int vi = faces[3 * f + k];
        const float* v = verts + ((size_t)b * kNV + vi) * 3;
        float4 o;
        o.x = v[0] + tx;
        o.y = v[1] + ty;
        o.z = v[2] + tz;
        o.w = 0.0f;
        dst[k] = o;
    }
}

// Cone-distance-field pair loss for one (intruder, receiver) triangle pair.
__device__ __forceinline__ float pair_loss(const float3 r0, const float3 r1, const float3 r2,
                                           const float3 i0, const float3 i1, const float3 i2) {
    // receiver frame
    float e1x = r1.x - r0.x, e1y = r1.y - r0.y, e1z = r1.z - r0.z;
    float e2x = r2.x - r0.x, e2y = r2.y - r0.y, e2z = r2.z - r0.z;
    float nx = e1y * e2z - e1z * e2y;
    float ny = e1z * e2x - e1x * e2z;
    float nz = e1x * e2y - e1y * e2x;
    float nn = sqrtf(nx * nx + ny * ny + nz * nz) + EPS_F;
    nx /= nn; ny /= nn; nz /= nn;
    float cx = (r0.x + r1.x + r2.x) / 3.0f;
    float cy = (r0.y + r1.y + r2.y) / 3.0f;
    float cz = (r0.z + r1.z + r2.z) / 3.0f;
    float d0x = r0.x - cx, d0y = r0.y - cy, d0z = r0.z - cz;
    float d1x = r1.x - cx, d1y = r1.y - cy, d1z = r1.z - cz;
    float d2x = r2.x - cx, d2y = r2.y - cy, d2z = r2.z - cz;
    float rad0 = sqrtf(d0x * d0x + d0y * d0y + d0z * d0z);
    float rad1 = sqrtf(d1x * d1x + d1y * d1y + d1z * d1z);
    float rad2 = sqrtf(d2x * d2x + d2y * d2y + d2z * d2z);
    float radius = fmaxf(fmaxf(rad0, rad1), rad2);
    float inv_rad = radius + EPS_F;

    float acc = 0.0f;
    const float3 iv[3] = {i0, i1, i2};
#pragma unroll
    for (int k = 0; k < 3; ++k) {
        float dx = iv[k].x - cx, dy = iv[k].y - cy, dz = iv[k].z - cz;
        float d = dx * nx + dy * ny + dz * nz;
        float px = dx - d * nx, py = dy - d * ny, pz = dz - d * nz;
        float radial = sqrtf(px * px + py * py + pz * pz);
        float fa = fmaxf(-d / SIGMA_F, 0.0f);
        float fb = fmaxf(1.0f - radial / inv_rad, 0.0f);
        float fd = fa * fb;
        acc += fd * fd;
    }
    return acc;
}

__device__ __forceinline__ float3 f3(float4 v) { return make_float3(v.x, v.y, v.z); }

// Main kernel, precomputed-triangle path: 1 thread per collision.
__global__ void __launch_bounds__(256)
pen_kernel(const int* __restrict__ coll,
           const float* __restrict__ tri,
           float* __restrict__ sums) {
    int p = blockIdx.y;
    int i = blockIdx.x * blockDim.x + threadIdx.x;
    float local = 0.0f;
    if (i < kC) {
        int2 idx = ((const int2*)coll)[(size_t)p * kC + i];
        if (idx.x != idx.y) {
            const float4* tb = (const float4*)tri + (size_t)p * kTF * 3;
            float4 r0 = tb[(size_t)idx.y * 3 + 0];
            float4 r1 = tb[(size_t)idx.y * 3 + 1];
            float4 r2 = tb[(size_t)idx.y * 3 + 2];
            float4 i0 = tb[(size_t)idx.x * 3 + 0];
            float4 i1 = tb[(size_t)idx.x * 3 + 1];
            float4 i2 = tb[(size_t)idx.x * 3 + 2];
            local = pair_loss(f3(r0), f3(r1), f3(r2), f3(i0), f3(i1), f3(i2));
        }
    }
    // wave(64) reduce, then block reduce, then 1 atomic per block
#pragma unroll
    for (int off = 32; off > 0; off >>= 1)
        local += __shfl_down(local, off, 64);
    __shared__ float red[4];
    int lane = threadIdx.x & 63;
    int wid  = threadIdx.x >> 6;
    if (lane == 0) red[wid] = local;
    __syncthreads();
    if (threadIdx.x == 0) {
        float s = red[0] + red[1] + red[2] + red[3];
        atomicAdd(&sums[p], s);
    }
}

// Fallback path: gather vertices directly (only used if ws too small for tri buffer)
__device__ __forceinline__ void load_tri_direct(const float* __restrict__ verts,
                                                const float* __restrict__ trans,
                                                const int* __restrict__ faces,
                                                int p, int t, float3 v[3]) {
    int half = (t >= kNF) ? 1 : 0;
    int b = 2 * p + half;
    int f = t - half * kNF;
    float tx = trans[3 * b + 0];
    float ty = trans[3 * b + 1];
    float tz = trans[3 * b + 2];
#pragma unroll
    for (int k = 0; k < 3; ++k) {
        int vi = faces[3 * f + k];
        const float* vp = verts + ((size_t)b * kNV + vi) * 3;
        v[k] = make_float3(vp[0] + tx, vp[1] + ty, vp[2] + tz);
    }
}

__global__ void __launch_bounds__(256)
pen_kernel_direct(const int* __restrict__ coll,
                  const float* __restrict__ verts,
                  const float* __restrict__ trans,
                  const int* __restrict__ faces,
                  float* __restrict__ sums) {
    int p = blockIdx.y;
    int i = blockIdx.x * blockDim.x + threadIdx.x;
    float local = 0.0f;
    if (i < kC) {
        int2 idx = ((const int2*)coll)[(size_t)p * kC + i];
        if (idx.x != idx.y) {
            float3 rv[3], iv[3];
            load_tri_direct(verts, trans, faces, p, idx.y, rv);
            load_tri_direct(verts, trans, faces, p, idx.x, iv);
            local = pair_loss(rv[0], rv[1], rv[2], iv[0], iv[1], iv[2]);
        }
    }
#pragma unroll
    for (int off = 32; off > 0; off >>= 1)
        local += __shfl_down(local, off, 64);
    __shared__ float red[4];
    int lane = threadIdx.x & 63;
    int wid  = threadIdx.x >> 6;
    if (lane == 0) red[wid] = local;
    __syncthreads();
    if (threadIdx.x == 0) {
        float s = red[0] + red[1] + red[2] + red[3];
        atomicAdd(&sums[p], s);
    }
}

__global__ void finalize_kernel(const float* __restrict__ sums, float* __restrict__ out) {
    if (threadIdx.x == 0 && blockIdx.x == 0) {
        float cnt = 0.0f, vals = 0.0f;
#pragma unroll
        for (int p = 0; p < kP; ++p) {
            float pen = sums[p];
            float keep = (pen < THRESH_F) ? 1.0f : 0.0f;
            cnt += keep;
            float s = 1.0f / (1.0f + expf(-pen / THRESH_F));
            vals += (s - 0.5f) * keep;
        }
        float loss = (cnt > 0.0f) ? (vals / fmaxf(cnt, 1.0f)) : 0.0f;
        out[0] = loss * WEIGHT_F;
    }
}

extern "C" void kernel_launch(void* const* d_in, const int* in_sizes, int n_in,
                              void* d_out, int out_size, void* d_ws, size_t ws_size,
                              hipStream_t stream) {
    const float* verts = (const float*)d_in[0];
    const float* trans = (const float*)d_in[1];
    const int*   faces = (const int*)d_in[2];
    const int*   coll  = (const int*)d_in[3];
    float* out  = (float*)d_out;
    float* sums = (float*)d_ws;

    const size_t tri_off_bytes = 256;
    const size_t tri_bytes = (size_t)kP * kTF * 12 * sizeof(float);

    init_sums_kernel<<<1, 64, 0, stream>>>(sums);

    dim3 grid_main(kC / 256, kP);
    if (ws_size >= tri_off_bytes + tri_bytes) {
        float* tri = (float*)((char*)d_ws + tri_off_bytes);
        int nt = kP * kTF;
        build_tris_kernel<<<(nt + 255) / 256, 256, 0, stream>>>(verts, trans, faces, tri);
        pen_kernel<<<grid_main, 256, 0, stream>>>(coll, tri, sums);
    } else {
        pen_kernel_direct<<<grid_main, 256, 0, stream>>>(coll, verts, trans, faces, sums);
    }
    finalize_kernel<<<1, 64, 0, stream>>>(sums, out);
}